// Round 8
// baseline (247.292 us; speedup 1.0000x reference)
//
#include <hip/hip_runtime.h>
#include <hip/hip_bf16.h>

#define B_ 4
#define D_ 128
#define H_ 128
#define W_ 32
#define CI 32
#define CO 64
#define OD 64
#define OH 64
#define OW 32
#define S_SPATIAL (OD*OH*OW)   // 131072
#define EPS 1e-5f
#define ALPHA 0.2f

#define XR 9                    // ih rows per kd-slice tile (oh-quad span)
#define XC 34                   // cols incl. W halo (c = iw+1, iw=-1..32, zero-padded)
#define UNITS (4*XR*XC)         // 1224 units of 8 bf16 (16B)
#define SLICEB (UNITS*16)       // 19584 B per slice
#define PLANEF (H_*W_*CI)       // floats per id plane (131072)

typedef __attribute__((ext_vector_type(8))) short short8;
typedef __attribute__((ext_vector_type(4))) float f32x4;

__device__ inline short f2bf(float f) {
    return __builtin_bit_cast(short, __float2bfloat16(f));   // RNE; pairs fuse to cvt_pk
}

__device__ inline short8 pack8(float4 a, float4 b) {
    short8 r;
    r[0]=f2bf(a.x); r[1]=f2bf(a.y); r[2]=f2bf(a.z); r[3]=f2bf(a.w);
    r[4]=f2bf(b.x); r[5]=f2bf(b.y); r[6]=f2bf(b.z); r[7]=f2bf(b.w);
    return r;
}

__global__ __launch_bounds__(512) void zero_ws_kernel(float* ws) {
    ws[threadIdx.x] = 0.f;   // 512 floats: sums + sumsqs
}

// Repack w[b,kd,kh,kw,ci,co] f32 -> bf16 lane-ordered B-fragments.
__global__ __launch_bounds__(64) void wprep_kernel(const float* __restrict__ w,
                                                   short* __restrict__ wp) {
    int blk = blockIdx.x;          // ((b*27+tap)*4+nf)
    int nf  = blk & 3;
    int tb  = blk >> 2;            // b*27+tap
    int l   = threadIdx.x;
    int l15 = l & 15, lhi = l >> 4;
    const float* wsrc = w + (size_t)tb * (CI*CO);   // [ci][co]
    short8 v;
#pragma unroll
    for (int j = 0; j < 8; ++j)
        v[j] = f2bf(wsrc[(lhi*8 + j)*CO + nf*16 + l15]);
    *(short8*)(wp + (size_t)blk*512 + l*8) = v;
}

// issue next slice's global loads into regs (fire early, consumed late)
#define ISSUE(plane) \
    _Pragma("unroll") for (int k = 0; k < 5; ++k) { \
        if (soff[k] >= 0) { \
            la[k] = *(const float4*)((plane) + soff[k]); \
            lb[k] = *(const float4*)((plane) + soff[k] + 4); \
        } else { \
            la[k] = make_float4(0.f,0.f,0.f,0.f); \
            lb[k] = la[k]; \
        } }

// cvt + ds_write the staged regs (vmcnt waits happen here, late)
#define WRITEB(base) \
    _Pragma("unroll") for (int k = 0; k < 5; ++k) { \
        int U_ = t + (k << 8); \
        if (U_ < UNITS) *(short8*)((base) + U_*16) = pack8(la[k], lb[k]); }

#define BARRIER_KEEP_VMEM() \
    asm volatile("s_waitcnt lgkmcnt(0)" ::: "memory"); \
    __builtin_amdgcn_s_barrier(); \
    __builtin_amdgcn_sched_barrier(0)

// Implicit-GEMM conv; bf16 LDS tile w/ halo (no masks in hot loop), reg-staged
// issue-early/write-late pipeline, raw lgkm-only barriers (VMEM floats across),
// 39168B LDS (stats aliased) -> 4 blocks/CU. Block = (b, od, oh-quad);
// wave wv owns oh row oh0+wv. Fused InstanceNorm stats.
__global__ __launch_bounds__(256, 4) void conv_mfma_kernel(const float* __restrict__ x,
                                                           const short* __restrict__ wp,
                                                           float* __restrict__ out,
                                                           float* __restrict__ ws) {
    const int bid = blockIdx.x;
    const int b   = bid >> 10;
    const int od  = (bid >> 4) & 63;
    const int oh0 = (bid & 15) << 2;
    const int t   = threadIdx.x;
    const int wv  = t >> 6;
    const int l   = t & 63;
    const int l15 = l & 15;
    const int lhi = l >> 4;

    const float* xb  = x + (size_t)b * (D_*PLANEF);
    const short* wpb = wp + (size_t)b * (27*2048);

    __shared__ __align__(16) char smem[2*SLICEB];   // 39168 B total
    char* buf0 = smem;
    char* buf1 = smem + SLICEB;

    // slice-invariant staging coords: unit U = t + k*256 -> [g][r][c]
    int soff[5];
#pragma unroll
    for (int k = 0; k < 5; ++k) {
        int U   = t + (k << 8);
        int g   = U / (XR*XC);
        int rem = U % (XR*XC);
        int r   = rem / XC;
        int c   = rem % XC;
        int ih  = oh0*2 + r;
        int iw  = c - 1;
        soff[k] = (U < UNITS && ih < H_ && (unsigned)iw < (unsigned)W_)
                    ? (ih*(W_*CI) + iw*CI + g*8) : -1;
    }

    f32x4 acc[2][4];
#pragma unroll
    for (int mf = 0; mf < 2; ++mf)
#pragma unroll
        for (int nf = 0; nf < 4; ++nf)
            acc[mf][nf] = (f32x4){0.f, 0.f, 0.f, 0.f};

    auto compute = [&](int kd, const char* base) {
        const short* wkd = wpb + (size_t)kd*(9*2048) + l*8;
#pragma unroll
        for (int kh = 0; kh < 3; ++kh) {
            const int r = 2*wv + kh;
#pragma unroll
            for (int kw = 0; kw < 3; ++kw) {
                const short* wpt = wkd + (kh*3 + kw)*2048;
                short8 bf0 = *(const short8*)(wpt);
                short8 bf1 = *(const short8*)(wpt + 512);
                short8 bf2 = *(const short8*)(wpt + 1024);
                short8 bf3 = *(const short8*)(wpt + 1536);
#pragma unroll
                for (int mf = 0; mf < 2; ++mf) {
                    int c = mf*16 + l15 + kw;                  // c = iw+1, zero-padded halo
                    int U = (lhi*XR + r)*XC + c;
                    short8 a = *(const short8*)(base + U*16);
                    acc[mf][0] = __builtin_amdgcn_mfma_f32_16x16x32_bf16(a, bf0, acc[mf][0], 0,0,0);
                    acc[mf][1] = __builtin_amdgcn_mfma_f32_16x16x32_bf16(a, bf1, acc[mf][1], 0,0,0);
                    acc[mf][2] = __builtin_amdgcn_mfma_f32_16x16x32_bf16(a, bf2, acc[mf][2], 0,0,0);
                    acc[mf][3] = __builtin_amdgcn_mfma_f32_16x16x32_bf16(a, bf3, acc[mf][3], 0,0,0);
                }
            }
        }
    };

    const int id0 = od*2;
    const float* p0 = xb + (size_t)id0 * PLANEF;
    const float* p1 = p0 + PLANEF;                 // id0+1 <= 127 always
    const bool has2 = (id0 + 2) < D_;
    const float* p2 = has2 ? (p1 + PLANEF) : p1;   // clamped; never computed

    float4 la[5], lb[5];

    // prologue: slice0 staged (latency exposed once); slice1 in flight
    ISSUE(p0);
    WRITEB(buf0);
    ISSUE(p1);
    BARRIER_KEEP_VMEM();            // buf0 visible; s1 loads still flying

    compute(0, buf0);               // covers s1 latency
    WRITEB(buf1);
    BARRIER_KEEP_VMEM();            // buf1 visible; buf0 reads done

    ISSUE(p2);
    __builtin_amdgcn_sched_barrier(0);   // pin: s2 loads issue before compute(1)
    compute(1, buf1);               // covers s2 latency
    WRITEB(buf0);
    BARRIER_KEEP_VMEM();            // buf0 (slice2) visible

    if (has2) compute(2, buf0);

    // C-write. C/D: row = lhi*4 + r, col = l15 [m89]
    const int oh = oh0 + wv;
    float* yb = out + (size_t)((b*OD + od)*OH + oh) * (OW*CO);
#pragma unroll
    for (int mf = 0; mf < 2; ++mf)
#pragma unroll
        for (int nf = 0; nf < 4; ++nf)
#pragma unroll
            for (int r = 0; r < 4; ++r) {
                int ow = mf*16 + lhi*4 + r;
                int co = nf*16 + l15;
                yb[ow*CO + co] = acc[mf][nf][r];
            }

    // Fused InstanceNorm stats (LDS scratch aliases the tile after full drain)
    __syncthreads();
    float* lsum = (float*)smem;            // [4][64]
    float* lsq  = (float*)(smem + 1024);   // [4][64]
    float csum[4], csq[4];
#pragma unroll
    for (int nf = 0; nf < 4; ++nf) {
        float s = 0.f, q = 0.f;
#pragma unroll
        for (int mf = 0; mf < 2; ++mf)
#pragma unroll
            for (int r = 0; r < 4; ++r) {
                float v = acc[mf][nf][r];
                s += v;
                q = fmaf(v, v, q);
            }
        s += __shfl_xor(s, 16, 64); s += __shfl_xor(s, 32, 64);
        q += __shfl_xor(q, 16, 64); q += __shfl_xor(q, 32, 64);
        csum[nf] = s; csq[nf] = q;
    }
    if (lhi == 0) {
#pragma unroll
        for (int nf = 0; nf < 4; ++nf) {
            lsum[wv*64 + nf*16 + l15] = csum[nf];
            lsq[wv*64 + nf*16 + l15]  = csq[nf];
        }
    }
    __syncthreads();
    if (t < 64) {
        float s = lsum[t] + lsum[64 + t] + lsum[128 + t] + lsum[192 + t];
        float q = lsq[t]  + lsq[64 + t]  + lsq[128 + t]  + lsq[192 + t];
        atomicAdd(&ws[b*64 + t], s);
        atomicAdd(&ws[256 + b*64 + t], q);
    }
}

// ws[0..255]=sum, ws[256..511]=sumsq  ->  ws[512..767]=scale, ws[768..1023]=shift
__global__ __launch_bounds__(256) void finalize_kernel(float* ws,
                                                       const float* __restrict__ gamma,
                                                       const float* __restrict__ beta) {
    int t = threadIdx.x;       // t = b*64 + co
    int co = t & 63;
    const float invS = 1.0f / (float)S_SPATIAL;
    float sum = ws[t];
    float sq  = ws[256 + t];
    float mu  = sum * invS;
    float var = sq * invS - mu*mu;
    float scale = rsqrtf(var + EPS) * gamma[co];
    ws[512 + t] = scale;
    ws[768 + t] = beta[co] - mu*scale;
}

// In-place normalize + leaky relu, float4 per thread.
__global__ __launch_bounds__(256) void norm_kernel(float* __restrict__ y,
                                                   const float* __restrict__ ws) {
    size_t i = (size_t)blockIdx.x * 256 + threadIdx.x;  // float4 index, total 8388608
    int b = (int)(i >> 21);                              // 2097152 float4 per sample
    const float4* scp = (const float4*)(ws + 512 + b*64);
    const float4* shp = (const float4*)(ws + 768 + b*64);
    float4 sc = scp[i & 15];
    float4 sh = shp[i & 15];
    float4 v = ((const float4*)y)[i];
    float4 r;
    r.x = fmaf(v.x, sc.x, sh.x);
    r.y = fmaf(v.y, sc.y, sh.y);
    r.z = fmaf(v.z, sc.z, sh.z);
    r.w = fmaf(v.w, sc.w, sh.w);
    r.x = r.x >= 0.f ? r.x : ALPHA * r.x;
    r.y = r.y >= 0.f ? r.y : ALPHA * r.y;
    r.z = r.z >= 0.f ? r.z : ALPHA * r.z;
    r.w = r.w >= 0.f ? r.w : ALPHA * r.w;
    ((float4*)y)[i] = r;
}

extern "C" void kernel_launch(void* const* d_in, const int* in_sizes, int n_in,
                              void* d_out, int out_size, void* d_ws, size_t ws_size,
                              hipStream_t stream) {
    const float* x     = (const float*)d_in[0];
    const float* w     = (const float*)d_in[1];
    const float* gamma = (const float*)d_in[2];
    const float* beta  = (const float*)d_in[3];
    float* out = (float*)d_out;
    float* ws  = (float*)d_ws;
    short* wp  = (short*)((char*)d_ws + 4096);   // bf16 B-fragments (442368 B)

    zero_ws_kernel<<<1, 512, 0, stream>>>(ws);
    wprep_kernel<<<B_*27*4, 64, 0, stream>>>(w, wp);
    conv_mfma_kernel<<<B_*OD*(OH/4), 256, 0, stream>>>(x, wp, out, ws);
    finalize_kernel<<<1, 256, 0, stream>>>(ws, gamma, beta);
    norm_kernel<<<32768, 256, 0, stream>>>(out, ws);
}

// Round 9
// 242.400 us; speedup vs baseline: 1.0202x; 1.0202x over previous
//
#include <hip/hip_runtime.h>
#include <hip/hip_bf16.h>

#define B_ 4
#define D_ 128
#define H_ 128
#define W_ 32
#define CI 32
#define CO 64
#define OD 64
#define OH 64
#define OW 32
#define S_SPATIAL (OD*OH*OW)   // 131072
#define EPS 1e-5f
#define ALPHA 0.2f

#define XR 9                    // ih rows per kd-slice tile (oh-quad span)
#define XC 34                   // cols incl. W halo (c = iw+1, iw=-1..32, zero-padded)
#define UNITS (4*XR*XC)         // 1224 units of 8 bf16 (16B)
#define XSLICEB (UNITS*16)      // 19584 B x tile
#define WSLICEB (9*4096)        // 36864 B: 9 taps x [4 nf][512 shorts]
#define PLANEF (H_*W_*CI)       // floats per id plane (131072)

typedef __attribute__((ext_vector_type(8))) short short8;
typedef __attribute__((ext_vector_type(4))) float f32x4;

__device__ inline short f2bf(float f) {
    return __builtin_bit_cast(short, __float2bfloat16(f));   // RNE; pairs fuse to cvt_pk
}

__device__ inline short8 pack8(float4 a, float4 b) {
    short8 r;
    r[0]=f2bf(a.x); r[1]=f2bf(a.y); r[2]=f2bf(a.z); r[3]=f2bf(a.w);
    r[4]=f2bf(b.x); r[5]=f2bf(b.y); r[6]=f2bf(b.z); r[7]=f2bf(b.w);
    return r;
}

__device__ inline void gload16(const void* g, const void* l) {
    // async 16B/lane global->LDS DMA; LDS dest = uniform base + lane*16.
    // Cannot be sunk/serialized by the register allocator (no dest VGPR).
    __builtin_amdgcn_global_load_lds(
        (const __attribute__((address_space(1))) void*)g,
        (__attribute__((address_space(3))) void*)l, 16, 0, 0);
}

__global__ __launch_bounds__(512) void zero_ws_kernel(float* ws) {
    ws[threadIdx.x] = 0.f;   // 512 floats: sums + sumsqs
}

// Repack w[b,kd,kh,kw,ci,co] f32 -> bf16 lane-ordered B-fragments.
__global__ __launch_bounds__(64) void wprep_kernel(const float* __restrict__ w,
                                                   short* __restrict__ wp) {
    int blk = blockIdx.x;          // ((b*27+tap)*4+nf)
    int nf  = blk & 3;
    int tb  = blk >> 2;            // b*27+tap
    int l   = threadIdx.x;
    int l15 = l & 15, lhi = l >> 4;
    const float* wsrc = w + (size_t)tb * (CI*CO);   // [ci][co]
    short8 v;
#pragma unroll
    for (int j = 0; j < 8; ++j)
        v[j] = f2bf(wsrc[(lhi*8 + j)*CO + nf*16 + l15]);
    *(short8*)(wp + (size_t)blk*512 + l*8) = v;
}

#define BARRIER_FULL() \
    asm volatile("s_waitcnt vmcnt(0) lgkmcnt(0)" ::: "memory"); \
    __builtin_amdgcn_s_barrier(); \
    __builtin_amdgcn_sched_barrier(0)

#define BARRIER_LGKM() \
    asm volatile("s_waitcnt lgkmcnt(0)" ::: "memory"); \
    __builtin_amdgcn_s_barrier(); \
    __builtin_amdgcn_sched_barrier(0)

// Implicit-GEMM conv. Per kd-slice 2-phase: {x reg-copy -> bf16 LDS (halo-padded),
// w DMA -> LDS} then pure-LDS compute (2 A ds_read + 4 B ds_read + 8 MFMA per tap,
// zero VMEM in hot loop). 56.4KB LDS -> 2 blocks/CU; cross-block TLP covers stage.
// Block = (b, od, oh-quad); wave wv owns oh row oh0+wv. Fused InstanceNorm stats.
__global__ __launch_bounds__(256, 2) void conv_mfma_kernel(const float* __restrict__ x,
                                                           const short* __restrict__ wp,
                                                           float* __restrict__ out,
                                                           float* __restrict__ ws) {
    const int bid = blockIdx.x;
    const int b   = bid >> 10;
    const int od  = (bid >> 4) & 63;
    const int oh0 = (bid & 15) << 2;
    const int t   = threadIdx.x;
    const int wv  = t >> 6;
    const int l   = t & 63;
    const int l15 = l & 15;
    const int lhi = l >> 4;

    const float* xb  = x + (size_t)b * (D_*PLANEF);
    const short* wpb = wp + (size_t)b * (27*2048);

    __shared__ __align__(16) char smem[XSLICEB + WSLICEB];   // 56448 B
    char* xbuf = smem;
    char* wbuf = smem + XSLICEB;

    // slice-invariant x staging coords: unit U = t + k*256 -> [g][r][c]
    int soff[5];
#pragma unroll
    for (int k = 0; k < 5; ++k) {
        int U   = t + (k << 8);
        int g   = U / (XR*XC);
        int rem = U % (XR*XC);
        int r   = rem / XC;
        int c   = rem % XC;
        int ih  = oh0*2 + r;
        int iw  = c - 1;
        soff[k] = (U < UNITS && ih < H_ && (unsigned)iw < (unsigned)W_)
                    ? (ih*(W_*CI) + iw*CI + g*8) : -1;
    }

    f32x4 acc[2][4];
#pragma unroll
    for (int mf = 0; mf < 2; ++mf)
#pragma unroll
        for (int nf = 0; nf < 4; ++nf)
            acc[mf][nf] = (f32x4){0.f, 0.f, 0.f, 0.f};

    // stage one kd-slice: w via fire-and-forget DMA, x via reg-copy + cvt
    auto stage = [&](const float* plane, int kd) {
        const short* wsrc = wpb + (size_t)kd * (9*2048);
#pragma unroll
        for (int k = 0; k < 9; ++k) {
            int u = t + (k << 8);                    // 0..2303, exact
            gload16(wsrc + u*8, wbuf + u*16);
        }
        float4 la[5], lb[5];
#pragma unroll
        for (int k = 0; k < 5; ++k) {
            if (soff[k] >= 0) {
                la[k] = *(const float4*)(plane + soff[k]);
                lb[k] = *(const float4*)(plane + soff[k] + 4);
            } else {
                la[k] = make_float4(0.f,0.f,0.f,0.f);
                lb[k] = la[k];
            }
        }
#pragma unroll
        for (int k = 0; k < 5; ++k) {
            int U = t + (k << 8);
            if (U < UNITS) *(short8*)(xbuf + U*16) = pack8(la[k], lb[k]);
        }
    };

    auto compute = [&]() {
#pragma unroll
        for (int kh = 0; kh < 3; ++kh) {
            const int r = 2*wv + kh;
#pragma unroll
            for (int kw = 0; kw < 3; ++kw) {
                const char* wpt = wbuf + (kh*3 + kw)*4096 + l*16;
                short8 bf0 = *(const short8*)(wpt);
                short8 bf1 = *(const short8*)(wpt + 1024);
                short8 bf2 = *(const short8*)(wpt + 2048);
                short8 bf3 = *(const short8*)(wpt + 3072);
#pragma unroll
                for (int mf = 0; mf < 2; ++mf) {
                    int c = mf*16 + l15 + kw;                  // c = iw+1, zero-padded halo
                    int U = (lhi*XR + r)*XC + c;
                    short8 a = *(const short8*)(xbuf + U*16);
                    acc[mf][0] = __builtin_amdgcn_mfma_f32_16x16x32_bf16(a, bf0, acc[mf][0], 0,0,0);
                    acc[mf][1] = __builtin_amdgcn_mfma_f32_16x16x32_bf16(a, bf1, acc[mf][1], 0,0,0);
                    acc[mf][2] = __builtin_amdgcn_mfma_f32_16x16x32_bf16(a, bf2, acc[mf][2], 0,0,0);
                    acc[mf][3] = __builtin_amdgcn_mfma_f32_16x16x32_bf16(a, bf3, acc[mf][3], 0,0,0);
                }
            }
        }
    };

    const int id0 = od*2;
    const float* p0 = xb + (size_t)id0 * PLANEF;
    const float* p1 = p0 + PLANEF;                 // id0+1 <= 127 always
    const bool has2 = (id0 + 2) < D_;
    const float* p2 = has2 ? (p1 + PLANEF) : p1;   // clamped; never computed

    stage(p0, 0);
    BARRIER_FULL();          // slice0 (x+w) visible
    compute();
    BARRIER_LGKM();          // all reads of bufs done
    stage(p1, 1);
    BARRIER_FULL();
    compute();
    BARRIER_LGKM();
    stage(p2, 2);
    BARRIER_FULL();
    if (has2) compute();     // block-uniform guard

    // C-write. C/D: row = lhi*4 + r, col = l15 [m89]
    const int oh = oh0 + wv;
    float* yb = out + (size_t)((b*OD + od)*OH + oh) * (OW*CO);
#pragma unroll
    for (int mf = 0; mf < 2; ++mf)
#pragma unroll
        for (int nf = 0; nf < 4; ++nf)
#pragma unroll
            for (int r = 0; r < 4; ++r) {
                int ow = mf*16 + lhi*4 + r;
                int co = nf*16 + l15;
                yb[ow*CO + co] = acc[mf][nf][r];
            }

    // Fused InstanceNorm stats (LDS scratch aliases the tile after full drain)
    __syncthreads();
    float* lsum = (float*)smem;            // [4][64]
    float* lsq  = (float*)(smem + 1024);   // [4][64]
    float csum[4], csq[4];
#pragma unroll
    for (int nf = 0; nf < 4; ++nf) {
        float s = 0.f, q = 0.f;
#pragma unroll
        for (int mf = 0; mf < 2; ++mf)
#pragma unroll
            for (int r = 0; r < 4; ++r) {
                float v = acc[mf][nf][r];
                s += v;
                q = fmaf(v, v, q);
            }
        s += __shfl_xor(s, 16, 64); s += __shfl_xor(s, 32, 64);
        q += __shfl_xor(q, 16, 64); q += __shfl_xor(q, 32, 64);
        csum[nf] = s; csq[nf] = q;
    }
    if (lhi == 0) {
#pragma unroll
        for (int nf = 0; nf < 4; ++nf) {
            lsum[wv*64 + nf*16 + l15] = csum[nf];
            lsq[wv*64 + nf*16 + l15]  = csq[nf];
        }
    }
    __syncthreads();
    if (t < 64) {
        float s = lsum[t] + lsum[64 + t] + lsum[128 + t] + lsum[192 + t];
        float q = lsq[t]  + lsq[64 + t]  + lsq[128 + t]  + lsq[192 + t];
        atomicAdd(&ws[b*64 + t], s);
        atomicAdd(&ws[256 + b*64 + t], q);
    }
}

// ws[0..255]=sum, ws[256..511]=sumsq  ->  ws[512..767]=scale, ws[768..1023]=shift
__global__ __launch_bounds__(256) void finalize_kernel(float* ws,
                                                       const float* __restrict__ gamma,
                                                       const float* __restrict__ beta) {
    int t = threadIdx.x;       // t = b*64 + co
    int co = t & 63;
    const float invS = 1.0f / (float)S_SPATIAL;
    float sum = ws[t];
    float sq  = ws[256 + t];
    float mu  = sum * invS;
    float var = sq * invS - mu*mu;
    float scale = rsqrtf(var + EPS) * gamma[co];
    ws[512 + t] = scale;
    ws[768 + t] = beta[co] - mu*scale;
}

// In-place normalize + leaky relu, float4 per thread.
__global__ __launch_bounds__(256) void norm_kernel(float* __restrict__ y,
                                                   const float* __restrict__ ws) {
    size_t i = (size_t)blockIdx.x * 256 + threadIdx.x;  // float4 index, total 8388608
    int b = (int)(i >> 21);                              // 2097152 float4 per sample
    const float4* scp = (const float4*)(ws + 512 + b*64);
    const float4* shp = (const float4*)(ws + 768 + b*64);
    float4 sc = scp[i & 15];
    float4 sh = shp[i & 15];
    float4 v = ((const float4*)y)[i];
    float4 r;
    r.x = fmaf(v.x, sc.x, sh.x);
    r.y = fmaf(v.y, sc.y, sh.y);
    r.z = fmaf(v.z, sc.z, sh.z);
    r.w = fmaf(v.w, sc.w, sh.w);
    r.x = r.x >= 0.f ? r.x : ALPHA * r.x;
    r.y = r.y >= 0.f ? r.y : ALPHA * r.y;
    r.z = r.z >= 0.f ? r.z : ALPHA * r.z;
    r.w = r.w >= 0.f ? r.w : ALPHA * r.w;
    ((float4*)y)[i] = r;
}

extern "C" void kernel_launch(void* const* d_in, const int* in_sizes, int n_in,
                              void* d_out, int out_size, void* d_ws, size_t ws_size,
                              hipStream_t stream) {
    const float* x     = (const float*)d_in[0];
    const float* w     = (const float*)d_in[1];
    const float* gamma = (const float*)d_in[2];
    const float* beta  = (const float*)d_in[3];
    float* out = (float*)d_out;
    float* ws  = (float*)d_ws;
    short* wp  = (short*)((char*)d_ws + 4096);   // bf16 B-fragments (442368 B)

    zero_ws_kernel<<<1, 512, 0, stream>>>(ws);
    wprep_kernel<<<B_*27*4, 64, 0, stream>>>(w, wp);
    conv_mfma_kernel<<<B_*OD*(OH/4), 256, 0, stream>>>(x, wp, out, ws);
    finalize_kernel<<<1, 256, 0, stream>>>(ws, gamma, beta);
    norm_kernel<<<32768, 256, 0, stream>>>(out, ws);
}